// Round 6
// baseline (286.449 us; speedup 1.0000x reference)
//
#include <hip/hip_runtime.h>
#include <hip/hip_cooperative_groups.h>
#include <math.h>

namespace cg = cooperative_groups;

#define NTOK 784
#define DIM 128
#define FFD 512
#define CGRID 247

// ================= Mega cooperative kernel: 5 phases, 4 grid syncs =================
__global__ __launch_bounds__(256) void aft_mega(
    const float* __restrict__ pu, const float* __restrict__ pv, float* __restrict__ W,
    const float* __restrict__ x, const float* __restrict__ g1, const float* __restrict__ b1n,
    const float* __restrict__ wq, const float* __restrict__ wk, const float* __restrict__ wv,
    float* __restrict__ q, float* __restrict__ ek, float* __restrict__ vv,
    float* __restrict__ nump, float* __restrict__ denp,
    const float* __restrict__ wo, const float* __restrict__ bo,
    const float* __restrict__ g2, const float* __restrict__ b2n,
    float* __restrict__ t2, float* __restrict__ fn,
    const float* __restrict__ w1, const float* __restrict__ b1f, float* __restrict__ ff1,
    const float* __restrict__ w2, const float* __restrict__ b2f, float* __restrict__ out) {
  __shared__ float smem[12800];   // 51.2 KB, phase-dependent layout
  cg::grid_group grid = cg::this_grid();
  int tid = threadIdx.x;

  // ============ P1: posw (169 jobs) || LN1+qkv (78 jobs) ============
  for (int job = blockIdx.x; job < 247; job += CGRID) {
    if (job < 169) {
      float (*As)[64] = (float(*)[64])smem;
      float (*Bs)[64] = (float(*)[64])(smem + 2048);
      int m0 = (job % 13) * 64, n0 = (job / 13) * 64;
      int tx = tid & 15, ty = tid >> 4;
      int r = tid >> 2, kq = (tid & 3) * 8;
      int gm = m0 + r; if (gm > NTOK - 1) gm = NTOK - 1;
      int gn = n0 + r; if (gn > NTOK - 1) gn = NTOK - 1;
      float acc[4][4] = {};
      for (int kt = 0; kt < 4; ++kt) {
        int k0 = kt * 32;
#pragma unroll
        for (int j = 0; j < 8; ++j) As[kq + j][r] = pu[gm * DIM + k0 + kq + j];
#pragma unroll
        for (int j = 0; j < 8; ++j) Bs[kq + j][r] = pv[gn * DIM + k0 + kq + j];
        __syncthreads();
#pragma unroll
        for (int kk = 0; kk < 32; ++kk) {
          float4 a4 = *(const float4*)&As[kk][ty * 4];
          float4 b4 = *(const float4*)&Bs[kk][tx * 4];
          float av[4] = {a4.x, a4.y, a4.z, a4.w};
          float bv[4] = {b4.x, b4.y, b4.z, b4.w};
#pragma unroll
          for (int i = 0; i < 4; ++i)
#pragma unroll
            for (int j = 0; j < 4; ++j) acc[i][j] = fmaf(av[i], bv[j], acc[i][j]);
        }
        __syncthreads();
      }
      int c0 = n0 + tx * 4;
      if (c0 + 3 < NTOK) {
#pragma unroll
        for (int i = 0; i < 4; ++i) {
          int gr = m0 + ty * 4 + i;
          if (gr < NTOK) {
            float4 o = {expf(acc[i][0]), expf(acc[i][1]), expf(acc[i][2]), expf(acc[i][3])};
            *(float4*)&W[gr * NTOK + c0] = o;
          }
        }
      }
    } else {
      float (*Xs)[64] = (float(*)[64])smem;            // [128][64]
      float (*Bq)[64] = (float(*)[64])(smem + 8192);   // [64][64]
      float* redS = smem + 12288;
      float* redQ = smem + 12544;
      int bid = job - 169;
      int m0 = (bid % 13) * 64;
      int ct = bid / 13;
      int wsel = ct >> 1;
      int n0 = (ct & 1) * 64;
      const float* B = (wsel == 0) ? wq : (wsel == 1) ? wk : wv;

      if (m0 + 64 <= NTOK) {
#pragma unroll
        for (int it = 0; it < 8; ++it) {
          int idx = it * 256 + tid;
          int c = idx >> 4, j4 = (idx & 15) * 4;
          float4 v = *(const float4*)&x[c * NTOK + m0 + j4];
          Xs[c][j4 + 0] = v.x; Xs[c][j4 + 1] = v.y; Xs[c][j4 + 2] = v.z; Xs[c][j4 + 3] = v.w;
        }
      } else {
#pragma unroll
        for (int it = 0; it < 8; ++it) {
          int idx = it * 256 + tid;
          int c = idx >> 4, j4 = (idx & 15) * 4;
#pragma unroll
          for (int u = 0; u < 4; ++u) {
            int n = m0 + j4 + u; if (n > NTOK - 1) n = NTOK - 1;
            Xs[c][j4 + u] = x[c * NTOK + n];
          }
        }
      }
      __syncthreads();

      int n = tid & 63, grp = tid >> 6;
      float s = 0.f, ss = 0.f;
      for (int c = grp * 32; c < grp * 32 + 32; ++c) { float v = Xs[c][n]; s += v; ss += v * v; }
      redS[grp * 64 + n] = s; redQ[grp * 64 + n] = ss;
      __syncthreads();
      float sum = redS[n] + redS[64 + n] + redS[128 + n] + redS[192 + n];
      float sq  = redQ[n] + redQ[64 + n] + redQ[128 + n] + redQ[192 + n];
      float mu = sum * (1.0f / DIM);
      float var = sq * (1.0f / DIM) - mu * mu;
      float rs = rsqrtf(var + 1e-5f);
      for (int c = grp * 32; c < grp * 32 + 32; ++c)
        Xs[c][n] = (Xs[c][n] - mu) * rs * g1[c] + b1n[c];

      int tx = tid & 15, ty = tid >> 4;
      int r = tid >> 2, kq = (tid & 3) * 16;
      float acc[4][4] = {};
#pragma unroll
      for (int h = 0; h < 2; ++h) {
#pragma unroll
        for (int j = 0; j < 4; ++j) {
          float4 v = *(const float4*)&B[(n0 + r) * DIM + h * 64 + kq + j * 4];
          Bq[kq + j * 4 + 0][r] = v.x; Bq[kq + j * 4 + 1][r] = v.y;
          Bq[kq + j * 4 + 2][r] = v.z; Bq[kq + j * 4 + 3][r] = v.w;
        }
        __syncthreads();
#pragma unroll 4
        for (int kk = 0; kk < 64; ++kk) {
          float4 a4 = *(const float4*)&Xs[h * 64 + kk][ty * 4];
          float4 b4 = *(const float4*)&Bq[kk][tx * 4];
          float av[4] = {a4.x, a4.y, a4.z, a4.w};
          float bv[4] = {b4.x, b4.y, b4.z, b4.w};
#pragma unroll
          for (int i = 0; i < 4; ++i)
#pragma unroll
            for (int j = 0; j < 4; ++j) acc[i][j] = fmaf(av[i], bv[j], acc[i][j]);
        }
        __syncthreads();
      }
      int c0 = n0 + tx * 4;
      float* dst = (wsel == 0) ? q : (wsel == 1) ? ek : vv;
#pragma unroll
      for (int i = 0; i < 4; ++i) {
        int gr = m0 + ty * 4 + i;
        if (gr < NTOK) {
          float4 o;
          if (wsel == 0) {
            o.x = 1.0f / (1.0f + expf(-acc[i][0]));
            o.y = 1.0f / (1.0f + expf(-acc[i][1]));
            o.z = 1.0f / (1.0f + expf(-acc[i][2]));
            o.w = 1.0f / (1.0f + expf(-acc[i][3]));
          } else if (wsel == 1) {
            o.x = expf(acc[i][0]); o.y = expf(acc[i][1]);
            o.z = expf(acc[i][2]); o.w = expf(acc[i][3]);
          } else {
            o.x = acc[i][0]; o.y = acc[i][1]; o.z = acc[i][2]; o.w = acc[i][3];
          }
          *(float4*)&dst[gr * DIM + c0] = o;
        }
      }
    }
  }
  __threadfence();
  grid.sync();

  // ============ P2: agg K-split 8, 208 jobs, 64x64 tiles ============
  for (int job = blockIdx.x; job < 208; job += CGRID) {
    float (*As)[64] = (float(*)[64])smem;
    float (*Bn)[64] = (float(*)[64])(smem + 2048);
    float (*Bd)[64] = (float(*)[64])(smem + 4096);
    int m0 = (job % 13) * 64;
    int d0 = ((job / 13) & 1) * 64;
    int s = job / 26;
    int tx = tid & 15, ty = tid >> 4;
    int ra = tid >> 2, ka = (tid & 3) * 8;
    int kb = tid >> 3, db = (tid & 7) * 8;
    int gm = m0 + ra; if (gm > NTOK - 1) gm = NTOK - 1;
    float an[4][4] = {}, ad[4][4] = {};
    int ktlo = (s * 25) / 8, kthi = ((s + 1) * 25) / 8;
    for (int kt = ktlo; kt < kthi; ++kt) {
      int k0 = kt * 32;
      if (k0 + 32 <= NTOK) {
        float4 a0 = *(const float4*)&W[gm * NTOK + k0 + ka];
        float4 a1 = *(const float4*)&W[gm * NTOK + k0 + ka + 4];
        As[ka + 0][ra] = a0.x; As[ka + 1][ra] = a0.y; As[ka + 2][ra] = a0.z; As[ka + 3][ra] = a0.w;
        As[ka + 4][ra] = a1.x; As[ka + 5][ra] = a1.y; As[ka + 6][ra] = a1.z; As[ka + 7][ra] = a1.w;
        int gk = k0 + kb;
        float4 e0 = *(const float4*)&ek[gk * DIM + d0 + db];
        float4 e1 = *(const float4*)&ek[gk * DIM + d0 + db + 4];
        float4 w0 = *(const float4*)&vv[gk * DIM + d0 + db];
        float4 w1_ = *(const float4*)&vv[gk * DIM + d0 + db + 4];
        Bd[kb][db + 0] = e0.x; Bd[kb][db + 1] = e0.y; Bd[kb][db + 2] = e0.z; Bd[kb][db + 3] = e0.w;
        Bd[kb][db + 4] = e1.x; Bd[kb][db + 5] = e1.y; Bd[kb][db + 6] = e1.z; Bd[kb][db + 7] = e1.w;
        Bn[kb][db + 0] = e0.x * w0.x; Bn[kb][db + 1] = e0.y * w0.y;
        Bn[kb][db + 2] = e0.z * w0.z; Bn[kb][db + 3] = e0.w * w0.w;
        Bn[kb][db + 4] = e1.x * w1_.x; Bn[kb][db + 5] = e1.y * w1_.y;
        Bn[kb][db + 6] = e1.z * w1_.z; Bn[kb][db + 7] = e1.w * w1_.w;
      } else {
#pragma unroll
        for (int j = 0; j < 8; ++j) {
          int gk = k0 + ka + j;
          As[ka + j][ra] = (gk < NTOK) ? W[gm * NTOK + gk] : 0.f;
        }
        int gk = k0 + kb;
        if (gk < NTOK) {
          float4 e0 = *(const float4*)&ek[gk * DIM + d0 + db];
          float4 e1 = *(const float4*)&ek[gk * DIM + d0 + db + 4];
          float4 w0 = *(const float4*)&vv[gk * DIM + d0 + db];
          float4 w1_ = *(const float4*)&vv[gk * DIM + d0 + db + 4];
          Bd[kb][db + 0] = e0.x; Bd[kb][db + 1] = e0.y; Bd[kb][db + 2] = e0.z; Bd[kb][db + 3] = e0.w;
          Bd[kb][db + 4] = e1.x; Bd[kb][db + 5] = e1.y; Bd[kb][db + 6] = e1.z; Bd[kb][db + 7] = e1.w;
          Bn[kb][db + 0] = e0.x * w0.x; Bn[kb][db + 1] = e0.y * w0.y;
          Bn[kb][db + 2] = e0.z * w0.z; Bn[kb][db + 3] = e0.w * w0.w;
          Bn[kb][db + 4] = e1.x * w1_.x; Bn[kb][db + 5] = e1.y * w1_.y;
          Bn[kb][db + 6] = e1.z * w1_.z; Bn[kb][db + 7] = e1.w * w1_.w;
        } else {
#pragma unroll
          for (int j = 0; j < 8; ++j) { Bd[kb][db + j] = 0.f; Bn[kb][db + j] = 0.f; }
        }
      }
      __syncthreads();
#pragma unroll
      for (int kk = 0; kk < 32; ++kk) {
        float4 a4 = *(const float4*)&As[kk][ty * 4];
        float4 n4 = *(const float4*)&Bn[kk][tx * 4];
        float4 d4 = *(const float4*)&Bd[kk][tx * 4];
        float av[4] = {a4.x, a4.y, a4.z, a4.w};
        float nv[4] = {n4.x, n4.y, n4.z, n4.w};
        float dv[4] = {d4.x, d4.y, d4.z, d4.w};
#pragma unroll
        for (int i = 0; i < 4; ++i)
#pragma unroll
          for (int j = 0; j < 4; ++j) {
            an[i][j] = fmaf(av[i], nv[j], an[i][j]);
            ad[i][j] = fmaf(av[i], dv[j], ad[i][j]);
          }
      }
      __syncthreads();
    }
#pragma unroll
    for (int i = 0; i < 4; ++i) {
      int gr = m0 + ty * 4 + i;
      if (gr < NTOK) {
        float4 on = {an[i][0], an[i][1], an[i][2], an[i][3]};
        float4 od = {ad[i][0], ad[i][1], ad[i][2], ad[i][3]};
        *(float4*)&nump[(s * NTOK + gr) * DIM + d0 + tx * 4] = on;
        *(float4*)&denp[(s * NTOK + gr) * DIM + d0 + tx * 4] = od;
      }
    }
  }
  __threadfence();
  grid.sync();

  // ============ P3: gate + O-proj + residual + LN2, 98 jobs x 8 rows ============
  for (int job = blockIdx.x; job < 98; job += CGRID) {
    float (*At)[9] = (float(*)[9])smem;              // [128][9]
    float (*Bp)[64] = (float(*)[64])(smem + 1152);   // [128][64]
    int m0 = job * 8;
    {
      int nn = tid >> 5, c4 = (tid & 31) * 4;
      int base = (m0 + nn) * DIM + c4;
      float4 qv = *(const float4*)&q[base];
      float4 nv = {0.f, 0.f, 0.f, 0.f}, dv = {0.f, 0.f, 0.f, 0.f};
#pragma unroll
      for (int s = 0; s < 8; ++s) {
        float4 a = *(const float4*)&nump[s * NTOK * DIM + base];
        float4 d = *(const float4*)&denp[s * NTOK * DIM + base];
        nv.x += a.x; nv.y += a.y; nv.z += a.z; nv.w += a.w;
        dv.x += d.x; dv.y += d.y; dv.z += d.z; dv.w += d.w;
      }
      At[c4 + 0][nn] = qv.x * (nv.x / dv.x);
      At[c4 + 1][nn] = qv.y * (nv.y / dv.y);
      At[c4 + 2][nn] = qv.z * (nv.z / dv.z);
      At[c4 + 3][nn] = qv.w * (nv.w / dv.w);
    }
    int ty = tid >> 5, txl = tid & 31;
    int rwo = tid >> 2, kq2 = (tid & 3) * 32;
    float accp[4] = {0.f, 0.f, 0.f, 0.f};
#pragma unroll
    for (int ch = 0; ch < 2; ++ch) {
#pragma unroll
      for (int u = 0; u < 8; ++u) {
        float4 v = *(const float4*)&wo[(ch * 64 + rwo) * DIM + kq2 + u * 4];
        Bp[kq2 + u * 4 + 0][rwo] = v.x; Bp[kq2 + u * 4 + 1][rwo] = v.y;
        Bp[kq2 + u * 4 + 2][rwo] = v.z; Bp[kq2 + u * 4 + 3][rwo] = v.w;
      }
      __syncthreads();
#pragma unroll 4
      for (int kk = 0; kk < DIM; ++kk) {
        float a = At[kk][ty];
        float2 b2 = *(const float2*)&Bp[kk][txl * 2];
        accp[ch * 2 + 0] = fmaf(a, b2.x, accp[ch * 2 + 0]);
        accp[ch * 2 + 1] = fmaf(a, b2.y, accp[ch * 2 + 1]);
      }
      __syncthreads();
    }
    int gn = m0 + ty;
    int cA = txl * 2, cB = 64 + txl * 2;
    float o0 = accp[0] + bo[cA]     + x[cA * NTOK + gn];
    float o1 = accp[1] + bo[cA + 1] + x[(cA + 1) * NTOK + gn];
    float o2 = accp[2] + bo[cB]     + x[cB * NTOK + gn];
    float o3 = accp[3] + bo[cB + 1] + x[(cB + 1) * NTOK + gn];
    float2 tA = {o0, o1}; *(float2*)&t2[gn * DIM + cA] = tA;
    float2 tB = {o2, o3}; *(float2*)&t2[gn * DIM + cB] = tB;
    float sv = o0 + o1 + o2 + o3;
    float ssv = o0 * o0 + o1 * o1 + o2 * o2 + o3 * o3;
#pragma unroll
    for (int off = 1; off < 32; off <<= 1) {
      sv += __shfl_xor(sv, off);
      ssv += __shfl_xor(ssv, off);
    }
    float mu = sv * (1.0f / DIM);
    float var = ssv * (1.0f / DIM) - mu * mu;
    float rs = rsqrtf(var + 1e-5f);
    float2 gA = *(const float2*)&g2[cA], bA = *(const float2*)&b2n[cA];
    float2 gB = *(const float2*)&g2[cB], bB = *(const float2*)&b2n[cB];
    float2 fA = {(o0 - mu) * rs * gA.x + bA.x, (o1 - mu) * rs * gA.y + bA.y};
    float2 fB = {(o2 - mu) * rs * gB.x + bB.x, (o3 - mu) * rs * gB.y + bB.y};
    *(float2*)&fn[gn * DIM + cA] = fA;
    *(float2*)&fn[gn * DIM + cB] = fB;
  }
  __threadfence();
  grid.sync();

  // ============ P4: ff1 = gelu(fn @ w1^T + b1), 104 jobs ============
  for (int job = blockIdx.x; job < 104; job += CGRID) {
    float (*As)[64] = (float(*)[64])smem;
    float (*Bs)[64] = (float(*)[64])(smem + 2048);
    int m0 = (job % 13) * 64, n0 = (job / 13) * 64;
    int tx = tid & 15, ty = tid >> 4;
    int r = tid >> 2, kq = (tid & 3) * 8;
    int gm = m0 + r; if (gm > NTOK - 1) gm = NTOK - 1;
    float acc[4][4] = {};
    for (int kt = 0; kt < 4; ++kt) {
      int k0 = kt * 32;
#pragma unroll
      for (int j = 0; j < 8; ++j) As[kq + j][r] = fn[gm * DIM + k0 + kq + j];
#pragma unroll
      for (int j = 0; j < 8; ++j) Bs[kq + j][r] = w1[(n0 + r) * DIM + k0 + kq + j];
      __syncthreads();
#pragma unroll
      for (int kk = 0; kk < 32; ++kk) {
        float4 a4 = *(const float4*)&As[kk][ty * 4];
        float4 b4 = *(const float4*)&Bs[kk][tx * 4];
        float av[4] = {a4.x, a4.y, a4.z, a4.w};
        float bv[4] = {b4.x, b4.y, b4.z, b4.w};
#pragma unroll
        for (int i = 0; i < 4; ++i)
#pragma unroll
          for (int j = 0; j < 4; ++j) acc[i][j] = fmaf(av[i], bv[j], acc[i][j]);
      }
      __syncthreads();
    }
    int c0 = n0 + tx * 4;
    float4 bias = *(const float4*)&b1f[c0];
    float bb[4] = {bias.x, bias.y, bias.z, bias.w};
#pragma unroll
    for (int i = 0; i < 4; ++i) {
      int gr = m0 + ty * 4 + i;
      if (gr < NTOK) {
        float4 o;
        float* op = &o.x;
#pragma unroll
        for (int j = 0; j < 4; ++j) {
          float xv = acc[i][j] + bb[j];
          op[j] = 0.5f * xv * (1.0f + erff(xv * 0.70710678118654752f));
        }
        *(float4*)&ff1[gr * FFD + c0] = o;
      }
    }
  }
  __threadfence();
  grid.sync();

  // ============ P5: ff2 + residual + out^T, 98 jobs (16x64), reg-prefetch ============
  for (int job = blockIdx.x; job < 98; job += CGRID) {
    float (*As)[17] = (float(*)[17])smem;            // [32][17]
    float (*Bs)[64] = (float(*)[64])(smem + 576);    // [32][64]
    int m0 = (job >> 1) * 16, n0 = (job & 1) * 64;
    int ra = tid >> 4, ka = (tid & 15) * 2;
    int rb = tid >> 2, kb = (tid & 3) * 8;
    int ty = tid >> 4, tx = tid & 15;
    float pa0, pa1; float4 pb0, pb1;
    {
      float2 a = *(const float2*)&ff1[(m0 + ra) * FFD + ka];
      pa0 = a.x; pa1 = a.y;
      pb0 = *(const float4*)&w2[(n0 + rb) * FFD + kb];
      pb1 = *(const float4*)&w2[(n0 + rb) * FFD + kb + 4];
    }
    float acc[4] = {0.f, 0.f, 0.f, 0.f};
    for (int kt = 0; kt < 16; ++kt) {
      As[ka][ra] = pa0; As[ka + 1][ra] = pa1;
      Bs[kb + 0][rb] = pb0.x; Bs[kb + 1][rb] = pb0.y; Bs[kb + 2][rb] = pb0.z; Bs[kb + 3][rb] = pb0.w;
      Bs[kb + 4][rb] = pb1.x; Bs[kb + 5][rb] = pb1.y; Bs[kb + 6][rb] = pb1.z; Bs[kb + 7][rb] = pb1.w;
      __syncthreads();
      if (kt < 15) {
        int k0 = (kt + 1) * 32;
        float2 a = *(const float2*)&ff1[(m0 + ra) * FFD + k0 + ka];
        pa0 = a.x; pa1 = a.y;
        pb0 = *(const float4*)&w2[(n0 + rb) * FFD + k0 + kb];
        pb1 = *(const float4*)&w2[(n0 + rb) * FFD + k0 + kb + 4];
      }
#pragma unroll
      for (int kk = 0; kk < 32; ++kk) {
        float a = As[kk][ty];
        float4 b4 = *(const float4*)&Bs[kk][tx * 4];
        acc[0] = fmaf(a, b4.x, acc[0]);
        acc[1] = fmaf(a, b4.y, acc[1]);
        acc[2] = fmaf(a, b4.z, acc[2]);
        acc[3] = fmaf(a, b4.w, acc[3]);
      }
      __syncthreads();
    }
    int gr = m0 + ty;
    int c = n0 + tx * 4;
    float4 bias = *(const float4*)&b2f[c];
    float4 t = *(const float4*)&t2[gr * DIM + c];
    out[(c + 0) * NTOK + gr] = acc[0] + bias.x + t.x;
    out[(c + 1) * NTOK + gr] = acc[1] + bias.y + t.y;
    out[(c + 2) * NTOK + gr] = acc[2] + bias.z + t.z;
    out[(c + 3) * NTOK + gr] = acc[3] + bias.w + t.w;
  }
}

// ===================== Fallback path (round-5 proven kernels) =====================
__global__ __launch_bounds__(256) void posw_qkv(
    const float* __restrict__ pu, const float* __restrict__ pv, float* __restrict__ W,
    const float* __restrict__ x, const float* __restrict__ g, const float* __restrict__ b,
    const float* __restrict__ wq, const float* __restrict__ wk, const float* __restrict__ wv,
    float* __restrict__ q, float* __restrict__ ek, float* __restrict__ vv) {
  __shared__ float smem[16896];
  int tid = threadIdx.x;
  if (blockIdx.x < 169) {
    float (*As)[64] = (float(*)[64])smem;
    float (*Bs)[64] = (float(*)[64])(smem + 2048);
    int pb = blockIdx.x;
    int m0 = (pb % 13) * 64, n0 = (pb / 13) * 64;
    int tx = tid & 15, ty = tid >> 4;
    int r = tid >> 2, kq = (tid & 3) * 8;
    int gm = m0 + r; if (gm > NTOK - 1) gm = NTOK - 1;
    int gn = n0 + r; if (gn > NTOK - 1) gn = NTOK - 1;
    float acc[4][4] = {};
    for (int kt = 0; kt < 4; ++kt) {
      int k0 = kt * 32;
#pragma unroll
      for (int j = 0; j < 8; ++j) As[kq + j][r] = pu[gm * DIM + k0 + kq + j];
#pragma unroll
      for (int j = 0; j < 8; ++j) Bs[kq + j][r] = pv[gn * DIM + k0 + kq + j];
      __syncthreads();
#pragma unroll
      for (int kk = 0; kk < 32; ++kk) {
        float4 a4 = *(const float4*)&As[kk][ty * 4];
        float4 b4 = *(const float4*)&Bs[kk][tx * 4];
        float av[4] = {a4.x, a4.y, a4.z, a4.w};
        float bv[4] = {b4.x, b4.y, b4.z, b4.w};
#pragma unroll
        for (int i = 0; i < 4; ++i)
#pragma unroll
          for (int j = 0; j < 4; ++j) acc[i][j] = fmaf(av[i], bv[j], acc[i][j]);
      }
      __syncthreads();
    }
    int c0 = n0 + tx * 4;
    if (c0 + 3 < NTOK) {
#pragma unroll
      for (int i = 0; i < 4; ++i) {
        int gr = m0 + ty * 4 + i;
        if (gr < NTOK) {
          float4 o = {expf(acc[i][0]), expf(acc[i][1]), expf(acc[i][2]), expf(acc[i][3])};
          *(float4*)&W[gr * NTOK + c0] = o;
        }
      }
    }
  } else {
    float (*Xs)[64] = (float(*)[64])smem;
    float (*Bs)[64] = (float(*)[64])(smem + 8192);
    float (*redS)[64] = (float(*)[64])(smem + 16384);
    float (*redQ)[64] = (float(*)[64])(smem + 16640);
    int bid = blockIdx.x - 169;
    int m0 = (bid % 13) * 64;
    int ct = bid / 13;
    int wsel = ct >> 1;
    int n0 = (ct & 1) * 64;
    const float* B = (wsel == 0) ? wq : (wsel == 1) ? wk : wv;
    if (m0 + 64 <= NTOK) {
#pragma unroll
      for (int it = 0; it < 8; ++it) {
        int idx = it * 256 + tid;
        int c = idx >> 4, j4 = (idx & 15) * 4;
        float4 v = *(const float4*)&x[c * NTOK + m0 + j4];
        Xs[c][j4 + 0] = v.x; Xs[c][j4 + 1] = v.y; Xs[c][j4 + 2] = v.z; Xs[c][j4 + 3] = v.w;
      }
    } else {
#pragma unroll
      for (int it = 0; it < 8; ++it) {
        int idx = it * 256 + tid;
        int c = idx >> 4, j4 = (idx & 15) * 4;
#pragma unroll
        for (int u = 0; u < 4; ++u) {
          int n = m0 + j4 + u; if (n > NTOK - 1) n = NTOK - 1;
          Xs[c][j4 + u] = x[c * NTOK + n];
        }
      }
    }
    __syncthreads();
    int n = tid & 63, grp = tid >> 6;
    float s = 0.f, ss = 0.f;
    for (int c = grp * 32; c < grp * 32 + 32; ++c) { float v = Xs[c][n]; s += v; ss += v * v; }
    redS[grp][n] = s; redQ[grp][n] = ss;
    __syncthreads();
    float sum = redS[0][n] + redS[1][n] + redS[2][n] + redS[3][n];
    float sq  = redQ[0][n] + redQ[1][n] + redQ[2][n] + redQ[3][n];
    float mu = sum * (1.0f / DIM);
    float var = sq * (1.0f / DIM) - mu * mu;
    float rs = rsqrtf(var + 1e-5f);
    for (int c = grp * 32; c < grp * 32 + 32; ++c)
      Xs[c][n] = (Xs[c][n] - mu) * rs * g[c] + b[c];
    int r = tid >> 2, kc = tid & 3;
#pragma unroll
    for (int j = 0; j < 8; ++j) {
      int k = kc * 32 + j * 4;
      float4 v = *(const float4*)&B[(n0 + r) * DIM + k];
      Bs[k + 0][r] = v.x; Bs[k + 1][r] = v.y; Bs[k + 2][r] = v.z; Bs[k + 3][r] = v.w;
    }
    __syncthreads();
    int tx = tid & 15, ty = tid >> 4;
    float acc[4][4] = {};
#pragma unroll 4
    for (int kk = 0; kk < DIM; ++kk) {
      float4 a4 = *(const float4*)&Xs[kk][ty * 4];
      float4 b4 = *(const float4*)&Bs[kk][tx * 4];
      float av[4] = {a4.x, a4.y, a4.z, a4.w};
      float bv[4] = {b4.x, b4.y, b4.z, b4.w};
#pragma unroll
      for (int i = 0; i < 4; ++i)
#pragma unroll
        for (int j = 0; j < 4; ++j) acc[i][j] = fmaf(av[i], bv[j], acc[i][j]);
    }
    int c0 = n0 + tx * 4;
    float* dst = (wsel == 0) ? q : (wsel == 1) ? ek : vv;
#pragma unroll
    for (int i = 0; i < 4; ++i) {
      int gr = m0 + ty * 4 + i;
      if (gr < NTOK) {
        float4 o;
        if (wsel == 0) {
          o.x = 1.0f / (1.0f + expf(-acc[i][0]));
          o.y = 1.0f / (1.0f + expf(-acc[i][1]));
          o.z = 1.0f / (1.0f + expf(-acc[i][2]));
          o.w = 1.0f / (1.0f + expf(-acc[i][3]));
        } else if (wsel == 1) {
          o.x = expf(acc[i][0]); o.y = expf(acc[i][1]);
          o.z = expf(acc[i][2]); o.w = expf(acc[i][3]);
        } else {
          o.x = acc[i][0]; o.y = acc[i][1]; o.z = acc[i][2]; o.w = acc[i][3];
        }
        *(float4*)&dst[gr * DIM + c0] = o;
      }
    }
  }
}

__global__ __launch_bounds__(512) void agg_gemm(
    const float* __restrict__ W, const float* __restrict__ ek,
    const float* __restrict__ vv, float* __restrict__ nump, float* __restrict__ denp) {
  __shared__ float As[32][64];
  __shared__ float Bn[32][64];
  __shared__ float Bd[32][64];
  int tid = threadIdx.x;
  int m0 = blockIdx.x * 64, d0 = blockIdx.y * 64, s = blockIdx.z;
  int tx = tid & 15, ty = tid >> 4;
  int ra = tid >> 3, ka = (tid & 7) * 4;
  int kb = tid >> 4, db = (tid & 15) * 4;
  int gm = m0 + ra; if (gm > NTOK - 1) gm = NTOK - 1;
  float an[2][4] = {}, ad[2][4] = {};
  int ktlo = (s * 25) / 8, kthi = ((s + 1) * 25) / 8;
  for (int kt = ktlo; kt < kthi; ++kt) {
    int k0 = kt * 32;
    if (k0 + 32 <= NTOK) {
      float4 a = *(const float4*)&W[gm * NTOK + k0 + ka];
      As[ka + 0][ra] = a.x; As[ka + 1][ra] = a.y;
      As[ka + 2][ra] = a.z; As[ka + 3][ra] = a.w;
      int gk = k0 + kb;
      float4 e = *(const float4*)&ek[gk * DIM + d0 + db];
      float4 w = *(const float4*)&vv[gk * DIM + d0 + db];
      Bd[kb][db + 0] = e.x; Bd[kb][db + 1] = e.y; Bd[kb][db + 2] = e.z; Bd[kb][db + 3] = e.w;
      Bn[kb][db + 0] = e.x * w.x; Bn[kb][db + 1] = e.y * w.y;
      Bn[kb][db + 2] = e.z * w.z; Bn[kb][db + 3] = e.w * w.w;
    } else {
#pragma unroll
      for (int j = 0; j < 4; ++j) {
        int gk = k0 + ka + j;
        As[ka + j][ra] = (gk < NTOK) ? W[gm * NTOK + gk] : 0.f;
      }
      int gk = k0 + kb;
      if (gk < NTOK) {
        float4 e = *(const float4*)&ek[gk * DIM + d0 + db];
        float4 w = *(const float4*)&vv[gk * DIM + d0 + db];
        Bd[kb][db + 0] = e.x; Bd[kb][db + 1] = e.y; Bd[kb][db + 2] = e.z; Bd[kb][db + 3] = e.w;
        Bn[kb][db + 0] = e.x * w.x; Bn[kb][db + 1] = e.y * w.y;
        Bn[kb][db + 2] = e.z * w.z; Bn[kb][db + 3] = e.w * w.w;
      } else {
        Bd[kb][db + 0] = 0.f; Bd[kb][db + 1] = 0.f; Bd[kb][db + 2] = 0.f; Bd[kb][db + 3] = 0.f;
        Bn[kb][db + 0] = 0.f; Bn[kb][db + 1] = 0.f; Bn[kb][db + 2] = 0.f; Bn[kb][db + 3] = 0.f;
      }
    }
    __syncthreads();
#pragma unroll
    for (int kk = 0; kk < 32; ++kk) {
      float2 a2 = *(const float2*)&As[kk][ty * 2];
      float4 n4 = *(const float4*)&Bn[kk][tx * 4];
      float4 d4 = *(const float4*)&Bd[kk][tx * 4];
      float av[2] = {a2.x, a2.y};
      float nv[4] = {n4.x, n4.y, n4.z, n4.w};
      float dv[4] = {d4.x, d4.y, d4.z, d4.w};
#pragma unroll
      for (int i = 0; i < 2; ++i)
#pragma unroll
        for (int j = 0; j < 4; ++j) {
          an[i][j] = fmaf(av[i], nv[j], an[i][j]);
          ad[i][j] = fmaf(av[i], dv[j], ad[i][j]);
        }
    }
    __syncthreads();
  }
#pragma unroll
  for (int i = 0; i < 2; ++i) {
    int gr = m0 + ty * 2 + i;
    if (gr < NTOK) {
      float4 on = {an[i][0], an[i][1], an[i][2], an[i][3]};
      float4 od = {ad[i][0], ad[i][1], ad[i][2], ad[i][3]};
      *(float4*)&nump[(s * NTOK + gr) * DIM + d0 + tx * 4] = on;
      *(float4*)&denp[(s * NTOK + gr) * DIM + d0 + tx * 4] = od;
    }
  }
}

__global__ __launch_bounds__(512) void proj_gate_ln(
    const float* __restrict__ q, const float* __restrict__ nump,
    const float* __restrict__ denp, const float* __restrict__ wo,
    const float* __restrict__ bo, const float* __restrict__ x,
    const float* __restrict__ g2, const float* __restrict__ b2n,
    float* __restrict__ t2, float* __restrict__ fn) {
  __shared__ float At[DIM][17];
  __shared__ float Bs[DIM][DIM];
  int tid = threadIdx.x;
  int m0 = blockIdx.x * 16;
  {
    int nn = tid >> 5, c4 = (tid & 31) * 4;
    int base = (m0 + nn) * DIM + c4;
    float4 qv = *(const float4*)&q[base];
    float4 nv = {0.f, 0.f, 0.f, 0.f}, dv = {0.f, 0.f, 0.f, 0.f};
#pragma unroll
    for (int s = 0; s < 8; ++s) {
      float4 a = *(const float4*)&nump[s * NTOK * DIM + base];
      float4 d = *(const float4*)&denp[s * NTOK * DIM + base];
      nv.x += a.x; nv.y += a.y; nv.z += a.z; nv.w += a.w;
      dv.x += d.x; dv.y += d.y; dv.z += d.z; dv.w += d.w;
    }
    At[c4 + 0][nn] = qv.x * (nv.x / dv.x);
    At[c4 + 1][nn] = qv.y * (nv.y / dv.y);
    At[c4 + 2][nn] = qv.z * (nv.z / dv.z);
    At[c4 + 3][nn] = qv.w * (nv.w / dv.w);
  }
  {
    int r = tid >> 2, kc = tid & 3;
#pragma unroll
    for (int j = 0; j < 8; ++j) {
      int k = kc * 32 + j * 4;
      float4 v = *(const float4*)&wo[r * DIM + k];
      Bs[k + 0][r] = v.x; Bs[k + 1][r] = v.y; Bs[k + 2][r] = v.z; Bs[k + 3][r] = v.w;
    }
  }
  __syncthreads();
  int ty = tid >> 5, tx = tid & 31;
  float acc[4] = {0.f, 0.f, 0.f, 0.f};
#pragma unroll 4
  for (int kk = 0; kk < DIM; ++kk) {
    float a = At[kk][ty];
    float4 b4 = *(const float4*)&Bs[kk][tx * 4];
    acc[0] = fmaf(a, b4.x, acc[0]);
    acc[1] = fmaf(a, b4.y, acc[1]);
    acc[2] = fmaf(a, b4.z, acc[2]);
    acc[3] = fmaf(a, b4.w, acc[3]);
  }
  int gn = m0 + ty;
  int c0 = tx * 4;
  float4 bias = *(const float4*)&bo[c0];
  float4 o;
  o.x = acc[0] + bias.x + x[(c0 + 0) * NTOK + gn];
  o.y = acc[1] + bias.y + x[(c0 + 1) * NTOK + gn];
  o.z = acc[2] + bias.z + x[(c0 + 2) * NTOK + gn];
  o.w = acc[3] + bias.w + x[(c0 + 3) * NTOK + gn];
  *(float4*)&t2[gn * DIM + c0] = o;
  float s = o.x + o.y + o.z + o.w;
  float ss = o.x * o.x + o.y * o.y + o.z * o.z + o.w * o.w;
#pragma unroll
  for (int off = 1; off < 32; off <<= 1) {
    s += __shfl_xor(s, off);
    ss += __shfl_xor(ss, off);
  }
  float mu = s * (1.0f / DIM);
  float var = ss * (1.0f / DIM) - mu * mu;
  float rs = rsqrtf(var + 1e-5f);
  float4 gg = *(const float4*)&g2[c0];
  float4 bb = *(const float4*)&b2n[c0];
  float4 f;
  f.x = (o.x - mu) * rs * gg.x + bb.x;
  f.y = (o.y - mu) * rs * gg.y + bb.y;
  f.z = (o.z - mu) * rs * gg.z + bb.z;
  f.w = (o.w - mu) * rs * gg.w + bb.w;
  *(float4*)&fn[gn * DIM + c0] = f;
}

__global__ __launch_bounds__(256) void ff1_gemm(
    const float* __restrict__ fn, const float* __restrict__ w1,
    const float* __restrict__ b1, float* __restrict__ ff1) {
  __shared__ float As[32][64];
  __shared__ float Bs[32][64];
  int tid = threadIdx.x;
  int m0 = blockIdx.x * 64, n0 = blockIdx.y * 64;
  int tx = tid & 15, ty = tid >> 4;
  int r = tid >> 2, kq = (tid & 3) * 8;
  int gm = m0 + r; if (gm > NTOK - 1) gm = NTOK - 1;
  float acc[4][4] = {};
  for (int kt = 0; kt < 4; ++kt) {
    int k0 = kt * 32;
#pragma unroll
    for (int j = 0; j < 8; ++j) As[kq + j][r] = fn[gm * DIM + k0 + kq + j];
#pragma unroll
    for (int j = 0; j < 8; ++j) Bs[kq + j][r] = w1[(n0 + r) * DIM + k0 + kq + j];
    __syncthreads();
#pragma unroll
    for (int kk = 0; kk < 32; ++kk) {
      float4 a4 = *(const float4*)&As[kk][ty * 4];
      float4 b4 = *(const float4*)&Bs[kk][tx * 4];
      float av[4] = {a4.x, a4.y, a4.z, a4.w};
      float bv[4] = {b4.x, b4.y, b4.z, b4.w};
#pragma unroll
      for (int i = 0; i < 4; ++i)
#pragma unroll
        for (int j = 0; j < 4; ++j) acc[i][j] = fmaf(av[i], bv[j], acc[i][j]);
    }
    __syncthreads();
  }
  int c0 = n0 + tx * 4;
  float4 bias = *(const float4*)&b1[c0];
  float bb[4] = {bias.x, bias.y, bias.z, bias.w};
#pragma unroll
  for (int i = 0; i < 4; ++i) {
    int gr = m0 + ty * 4 + i;
    if (gr < NTOK) {
      float4 o;
      float* op = &o.x;
#pragma unroll
      for (int j = 0; j < 4; ++j) {
        float xv = acc[i][j] + bb[j];
        op[j] = 0.5f * xv * (1.0f + erff(xv * 0.70710678118654752f));
      }
      *(float4*)&ff1[gr * FFD + c0] = o;
    }
  }
}

__global__ __launch_bounds__(512) void ff2_gemm(
    const float* __restrict__ ff1, const float* __restrict__ w2,
    const float* __restrict__ b2, const float* __restrict__ t2, float* __restrict__ out) {
  __shared__ float As[32][64];
  __shared__ float Bs[32][64];
  int tid = threadIdx.x;
  int m0 = blockIdx.x * 64, n0 = blockIdx.y * 64;
  int tx = tid & 15, ty = tid >> 4;
  int ra = tid >> 3, ka = (tid & 7) * 4;
  int gm = m0 + ra; if (gm > NTOK - 1) gm = NTOK - 1;
  float acc[2][4] = {};
  for (int kt = 0; kt < 16; ++kt) {
    int k0 = kt * 32;
    {
      float4 a = *(const float4*)&ff1[gm * FFD + k0 + ka];
      As[ka + 0][ra] = a.x; As[ka + 1][ra] = a.y;
      As[ka + 2][ra] = a.z; As[ka + 3][ra] = a.w;
      float4 bb = *(const float4*)&w2[(n0 + ra) * FFD + k0 + ka];
      Bs[ka + 0][ra] = bb.x; Bs[ka + 1][ra] = bb.y;
      Bs[ka + 2][ra] = bb.z; Bs[ka + 3][ra] = bb.w;
    }
    __syncthreads();
#pragma unroll
    for (int kk = 0; kk < 32; ++kk) {
      float2 a2 = *(const float2*)&As[kk][ty * 2];
      float4 b4 = *(const float4*)&Bs[kk][tx * 4];
      float av[2] = {a2.x, a2.y};
      float bv[4] = {b4.x, b4.y, b4.z, b4.w};
#pragma unroll
      for (int i = 0; i < 2; ++i)
#pragma unroll
        for (int j = 0; j < 4; ++j) acc[i][j] = fmaf(av[i], bv[j], acc[i][j]);
    }
    __syncthreads();
  }
  int c = n0 + tx * 4;
  float4 bias = *(const float4*)&b2[c];
#pragma unroll
  for (int i = 0; i < 2; ++i) {
    int gr = m0 + ty * 2 + i;
    if (gr < NTOK) {
      float4 t = *(const float4*)&t2[gr * DIM + c];
      out[(c + 0) * NTOK + gr] = acc[i][0] + bias.x + t.x;
      out[(c + 1) * NTOK + gr] = acc[i][1] + bias.y + t.y;
      out[(c + 2) * NTOK + gr] = acc[i][2] + bias.z + t.z;
      out[(c + 3) * NTOK + gr] = acc[i][3] + bias.w + t.w;
    }
  }
}

extern "C" void kernel_launch(void* const* d_in, const int* in_sizes, int n_in,
                              void* d_out, int out_size, void* d_ws, size_t ws_size,
                              hipStream_t stream) {
  const float* x   = (const float*)d_in[0];
  const float* wq  = (const float*)d_in[1];
  const float* wk  = (const float*)d_in[2];
  const float* wv  = (const float*)d_in[3];
  const float* wo  = (const float*)d_in[4];
  const float* bo  = (const float*)d_in[5];
  const float* pu  = (const float*)d_in[6];
  const float* pv  = (const float*)d_in[7];
  const float* g1  = (const float*)d_in[8];
  const float* b1n = (const float*)d_in[9];
  const float* g2  = (const float*)d_in[10];
  const float* b2n = (const float*)d_in[11];
  const float* w1  = (const float*)d_in[12];
  const float* b1f = (const float*)d_in[13];
  const float* w2  = (const float*)d_in[14];
  const float* b2f = (const float*)d_in[15];
  float* out = (float*)d_out;

  float* ws = (float*)d_ws;
  float* q    = ws;                 // [784,128]
  float* ek   = ws + 100352;
  float* vv   = ws + 200704;
  float* t2   = ws + 301056;
  float* fn   = ws + 401408;
  float* W    = ws + 501760;        // [784,784]; reused as ff1 [784,512]
  float* ff1p = W;
  float* nump = ws + 1116416;       // [8,784,128]
  float* denp = ws + 1919232;       // [8,784,128]

  void* args[] = {
      (void*)&pu, (void*)&pv, (void*)&W,
      (void*)&x, (void*)&g1, (void*)&b1n,
      (void*)&wq, (void*)&wk, (void*)&wv,
      (void*)&q, (void*)&ek, (void*)&vv,
      (void*)&nump, (void*)&denp,
      (void*)&wo, (void*)&bo, (void*)&g2, (void*)&b2n,
      (void*)&t2, (void*)&fn,
      (void*)&w1, (void*)&b1f, (void*)&ff1p,
      (void*)&w2, (void*)&b2f, (void*)&out};

  hipError_t e = hipLaunchCooperativeKernel((const void*)aft_mega, dim3(CGRID),
                                            dim3(256), args, 0, stream);
  if (e != hipSuccess) {
    // Fallback: proven 5-kernel path
    posw_qkv<<<247, 256, 0, stream>>>(pu, pv, W, x, g1, b1n, wq, wk, wv, q, ek, vv);
    agg_gemm<<<dim3(13, 2, 8), 512, 0, stream>>>(W, ek, vv, nump, denp);
    proj_gate_ln<<<49, 512, 0, stream>>>(q, nump, denp, wo, bo, x, g2, b2n, t2, fn);
    ff1_gemm<<<dim3(13, 8), 256, 0, stream>>>(fn, w1, b1f, ff1p);
    ff2_gemm<<<dim3(13, 2), 512, 0, stream>>>(ff1p, w2, b2f, t2, out);
  }
}

// Round 7
// 52.754 us; speedup vs baseline: 5.4299x; 5.4299x over previous
//
#include <hip/hip_runtime.h>
#include <math.h>

#define NTOK 784
#define DIM 128
#define FFD 512

// ========== K1: posw (169 blocks, single-stage) || LN1+qkv (78 blocks) ==========
__global__ __launch_bounds__(256) void posw_qkv2(
    const float* __restrict__ pu, const float* __restrict__ pv, float* __restrict__ W,
    const float* __restrict__ x, const float* __restrict__ g, const float* __restrict__ b,
    const float* __restrict__ wq, const float* __restrict__ wk, const float* __restrict__ wv,
    float* __restrict__ q, float* __restrict__ ek, float* __restrict__ vv) {
  __shared__ float smem[16384];  // 64 KB union
  int tid = threadIdx.x;

  if (blockIdx.x < 169) {
    // single-stage: full 64x128 A and B tiles, ONE sync
    float (*As)[64] = (float(*)[64])smem;           // [128][64] k-major
    float (*Bs)[64] = (float(*)[64])(smem + 8192);  // [128][64] k-major
    int m0 = (blockIdx.x % 13) * 64, n0 = (blockIdx.x / 13) * 64;
    int r = tid >> 2, kq = (tid & 3) * 32;
    int gm = min(m0 + r, NTOK - 1), gn = min(n0 + r, NTOK - 1);
#pragma unroll
    for (int j = 0; j < 8; ++j) {
      float4 a = *(const float4*)&pu[gm * DIM + kq + j * 4];
      As[kq + j * 4 + 0][r] = a.x; As[kq + j * 4 + 1][r] = a.y;
      As[kq + j * 4 + 2][r] = a.z; As[kq + j * 4 + 3][r] = a.w;
      float4 bv = *(const float4*)&pv[gn * DIM + kq + j * 4];
      Bs[kq + j * 4 + 0][r] = bv.x; Bs[kq + j * 4 + 1][r] = bv.y;
      Bs[kq + j * 4 + 2][r] = bv.z; Bs[kq + j * 4 + 3][r] = bv.w;
    }
    __syncthreads();
    int tx = tid & 15, ty = tid >> 4;
    float acc[4][4] = {};
#pragma unroll 8
    for (int kk = 0; kk < DIM; ++kk) {
      float4 a4 = *(const float4*)&As[kk][ty * 4];
      float4 b4 = *(const float4*)&Bs[kk][tx * 4];
      float av[4] = {a4.x, a4.y, a4.z, a4.w};
      float bv[4] = {b4.x, b4.y, b4.z, b4.w};
#pragma unroll
      for (int i = 0; i < 4; ++i)
#pragma unroll
        for (int j = 0; j < 4; ++j) acc[i][j] = fmaf(av[i], bv[j], acc[i][j]);
    }
    int c0 = n0 + tx * 4;
    if (c0 + 3 < NTOK) {
#pragma unroll
      for (int i = 0; i < 4; ++i) {
        int gr = m0 + ty * 4 + i;
        if (gr < NTOK) {
          float4 o = {expf(acc[i][0]), expf(acc[i][1]), expf(acc[i][2]), expf(acc[i][3])};
          *(float4*)&W[gr * NTOK + c0] = o;
        }
      }
    }
  } else {
    float (*Xs)[64] = (float(*)[64])smem;            // [128][64]
    float (*Bq)[64] = (float(*)[64])(smem + 8192);   // [64][64]
    float* redS = smem + 12288;
    float* redQ = smem + 12544;
    int bid = blockIdx.x - 169;
    int m0 = (bid % 13) * 64;
    int ct = bid / 13;
    int wsel = ct >> 1;
    int n0 = (ct & 1) * 64;
    const float* B = (wsel == 0) ? wq : (wsel == 1) ? wk : wv;

    if (m0 + 64 <= NTOK) {
#pragma unroll
      for (int it = 0; it < 8; ++it) {
        int idx = it * 256 + tid;
        int c = idx >> 4, j4 = (idx & 15) * 4;
        float4 v = *(const float4*)&x[c * NTOK + m0 + j4];
        Xs[c][j4 + 0] = v.x; Xs[c][j4 + 1] = v.y; Xs[c][j4 + 2] = v.z; Xs[c][j4 + 3] = v.w;
      }
    } else {
#pragma unroll
      for (int it = 0; it < 8; ++it) {
        int idx = it * 256 + tid;
        int c = idx >> 4, j4 = (idx & 15) * 4;
#pragma unroll
        for (int u = 0; u < 4; ++u) {
          int n = min(m0 + j4 + u, NTOK - 1);
          Xs[c][j4 + u] = x[c * NTOK + n];
        }
      }
    }
    __syncthreads();

    int n = tid & 63, grp = tid >> 6;
    float s = 0.f, ss = 0.f;
    for (int c = grp * 32; c < grp * 32 + 32; ++c) { float v = Xs[c][n]; s += v; ss += v * v; }
    redS[grp * 64 + n] = s; redQ[grp * 64 + n] = ss;
    __syncthreads();
    float sum = redS[n] + redS[64 + n] + redS[128 + n] + redS[192 + n];
    float sq  = redQ[n] + redQ[64 + n] + redQ[128 + n] + redQ[192 + n];
    float mu = sum * (1.0f / DIM);
    float var = sq * (1.0f / DIM) - mu * mu;
    float rs = rsqrtf(var + 1e-5f);
    for (int c = grp * 32; c < grp * 32 + 32; ++c)
      Xs[c][n] = (Xs[c][n] - mu) * rs * g[c] + b[c];

    int tx = tid & 15, ty = tid >> 4;
    int r = tid >> 2, kq = (tid & 3) * 16;
    float acc[4][4] = {};
#pragma unroll
    for (int h = 0; h < 2; ++h) {
#pragma unroll
      for (int j = 0; j < 4; ++j) {
        float4 v = *(const float4*)&B[(n0 + r) * DIM + h * 64 + kq + j * 4];
        Bq[kq + j * 4 + 0][r] = v.x; Bq[kq + j * 4 + 1][r] = v.y;
        Bq[kq + j * 4 + 2][r] = v.z; Bq[kq + j * 4 + 3][r] = v.w;
      }
      __syncthreads();
#pragma unroll 4
      for (int kk = 0; kk < 64; ++kk) {
        float4 a4 = *(const float4*)&Xs[h * 64 + kk][ty * 4];
        float4 b4 = *(const float4*)&Bq[kk][tx * 4];
        float av[4] = {a4.x, a4.y, a4.z, a4.w};
        float bv[4] = {b4.x, b4.y, b4.z, b4.w};
#pragma unroll
        for (int i = 0; i < 4; ++i)
#pragma unroll
          for (int j = 0; j < 4; ++j) acc[i][j] = fmaf(av[i], bv[j], acc[i][j]);
      }
      __syncthreads();
    }
    int c0 = n0 + tx * 4;
    float* dst = (wsel == 0) ? q : (wsel == 1) ? ek : vv;
#pragma unroll
    for (int i = 0; i < 4; ++i) {
      int gr = m0 + ty * 4 + i;
      if (gr < NTOK) {
        float4 o;
        if (wsel == 0) {
          o.x = 1.0f / (1.0f + expf(-acc[i][0]));
          o.y = 1.0f / (1.0f + expf(-acc[i][1]));
          o.z = 1.0f / (1.0f + expf(-acc[i][2]));
          o.w = 1.0f / (1.0f + expf(-acc[i][3]));
        } else if (wsel == 1) {
          o.x = expf(acc[i][0]); o.y = expf(acc[i][1]);
          o.z = expf(acc[i][2]); o.w = expf(acc[i][3]);
        } else {
          o.x = acc[i][0]; o.y = acc[i][1]; o.z = acc[i][2]; o.w = acc[i][3];
        }
        *(float4*)&dst[gr * DIM + c0] = o;
      }
    }
  }
}

// ========== K2: agg, split-8, chunked single-stage (<=3 tiles), grid (13,2,8), 256 thr ==========
__global__ __launch_bounds__(256) void agg8(
    const float* __restrict__ W, const float* __restrict__ ek,
    const float* __restrict__ vv, float* __restrict__ nump, float* __restrict__ denp) {
  __shared__ float As[96][64];
  __shared__ float Bn[96][64];
  __shared__ float Bd[96][64];
  int tid = threadIdx.x;
  int m0 = blockIdx.x * 64, d0 = blockIdx.y * 64, sp = blockIdx.z;
  int tx = tid & 15, ty = tid >> 4;
  int ra = tid >> 2, ka = (tid & 3) * 8;
  int kb = tid >> 3, db = (tid & 7) * 8;
  int gm = min(m0 + ra, NTOK - 1);
  float an[4][4] = {}, ad[4][4] = {};
  int tlo = (sp * 25) / 8, thi = ((sp + 1) * 25) / 8;
  for (int base = tlo; base < thi; base += 3) {
    int nt = min(3, thi - base);
    for (int t = 0; t < nt; ++t) {
      int k0 = (base + t) * 32;
      int lk = t * 32;
      if (k0 + 32 <= NTOK) {
        float4 a0 = *(const float4*)&W[gm * NTOK + k0 + ka];
        float4 a1 = *(const float4*)&W[gm * NTOK + k0 + ka + 4];
        As[lk + ka + 0][ra] = a0.x; As[lk + ka + 1][ra] = a0.y;
        As[lk + ka + 2][ra] = a0.z; As[lk + ka + 3][ra] = a0.w;
        As[lk + ka + 4][ra] = a1.x; As[lk + ka + 5][ra] = a1.y;
        As[lk + ka + 6][ra] = a1.z; As[lk + ka + 7][ra] = a1.w;
        int gk = k0 + kb;
        float4 e0 = *(const float4*)&ek[gk * DIM + d0 + db];
        float4 e1 = *(const float4*)&ek[gk * DIM + d0 + db + 4];
        float4 w0 = *(const float4*)&vv[gk * DIM + d0 + db];
        float4 w1_ = *(const float4*)&vv[gk * DIM + d0 + db + 4];
        Bd[lk + kb][db + 0] = e0.x; Bd[lk + kb][db + 1] = e0.y;
        Bd[lk + kb][db + 2] = e0.z; Bd[lk + kb][db + 3] = e0.w;
        Bd[lk + kb][db + 4] = e1.x; Bd[lk + kb][db + 5] = e1.y;
        Bd[lk + kb][db + 6] = e1.z; Bd[lk + kb][db + 7] = e1.w;
        Bn[lk + kb][db + 0] = e0.x * w0.x; Bn[lk + kb][db + 1] = e0.y * w0.y;
        Bn[lk + kb][db + 2] = e0.z * w0.z; Bn[lk + kb][db + 3] = e0.w * w0.w;
        Bn[lk + kb][db + 4] = e1.x * w1_.x; Bn[lk + kb][db + 5] = e1.y * w1_.y;
        Bn[lk + kb][db + 6] = e1.z * w1_.z; Bn[lk + kb][db + 7] = e1.w * w1_.w;
      } else {
#pragma unroll
        for (int j = 0; j < 8; ++j) {
          int gk = k0 + ka + j;
          As[lk + ka + j][ra] = (gk < NTOK) ? W[gm * NTOK + gk] : 0.f;
        }
        int gk = k0 + kb;
        if (gk < NTOK) {
          float4 e0 = *(const float4*)&ek[gk * DIM + d0 + db];
          float4 e1 = *(const float4*)&ek[gk * DIM + d0 + db + 4];
          float4 w0 = *(const float4*)&vv[gk * DIM + d0 + db];
          float4 w1_ = *(const float4*)&vv[gk * DIM + d0 + db + 4];
          Bd[lk + kb][db + 0] = e0.x; Bd[lk + kb][db + 1] = e0.y;
          Bd[lk + kb][db + 2] = e0.z; Bd[lk + kb][db + 3] = e0.w;
          Bd[lk + kb][db + 4] = e1.x; Bd[lk + kb][db + 5] = e1.y;
          Bd[lk + kb][db + 6] = e1.z; Bd[lk + kb][db + 7] = e1.w;
          Bn[lk + kb][db + 0] = e0.x * w0.x; Bn[lk + kb][db + 1] = e0.y * w0.y;
          Bn[lk + kb][db + 2] = e0.z * w0.z; Bn[lk + kb][db + 3] = e0.w * w0.w;
          Bn[lk + kb][db + 4] = e1.x * w1_.x; Bn[lk + kb][db + 5] = e1.y * w1_.y;
          Bn[lk + kb][db + 6] = e1.z * w1_.z; Bn[lk + kb][db + 7] = e1.w * w1_.w;
        } else {
#pragma unroll
          for (int j = 0; j < 8; ++j) { Bd[lk + kb][db + j] = 0.f; Bn[lk + kb][db + j] = 0.f; }
        }
      }
    }
    __syncthreads();
    int nk = nt * 32;
    for (int kk = 0; kk < nk; ++kk) {
      float4 a4 = *(const float4*)&As[kk][ty * 4];
      float4 n4 = *(const float4*)&Bn[kk][tx * 4];
      float4 d4 = *(const float4*)&Bd[kk][tx * 4];
      float av[4] = {a4.x, a4.y, a4.z, a4.w};
      float nv[4] = {n4.x, n4.y, n4.z, n4.w};
      float dv[4] = {d4.x, d4.y, d4.z, d4.w};
#pragma unroll
      for (int i = 0; i < 4; ++i)
#pragma unroll
        for (int j = 0; j < 4; ++j) {
          an[i][j] = fmaf(av[i], nv[j], an[i][j]);
          ad[i][j] = fmaf(av[i], dv[j], ad[i][j]);
        }
    }
    __syncthreads();
  }
#pragma unroll
  for (int i = 0; i < 4; ++i) {
    int gr = m0 + ty * 4 + i;
    if (gr < NTOK) {
      float4 on = {an[i][0], an[i][1], an[i][2], an[i][3]};
      float4 od = {ad[i][0], ad[i][1], ad[i][2], ad[i][3]};
      *(float4*)&nump[(sp * NTOK + gr) * DIM + d0 + tx * 4] = on;
      *(float4*)&denp[(sp * NTOK + gr) * DIM + d0 + tx * 4] = od;
    }
  }
}

// ========== K3: gate + O-proj + residual + LN2 + out-init, 98 blocks x 256 thr ==========
__global__ __launch_bounds__(256) void gate_proj_ln(
    const float* __restrict__ q, const float* __restrict__ nump,
    const float* __restrict__ denp, const float* __restrict__ wo,
    const float* __restrict__ bo, const float* __restrict__ x,
    const float* __restrict__ g2, const float* __restrict__ b2n,
    const float* __restrict__ b2f, float* __restrict__ fn, float* __restrict__ out) {
  __shared__ float At[DIM][9];     // attn tile k-major, 8 rows
  __shared__ float Bs[DIM][DIM];   // full wo, k-major
  int tid = threadIdx.x;
  int m0 = blockIdx.x * 8;         // 98*8 = 784

  {
    int nn = tid >> 5, c4 = (tid & 31) * 4;
    int base = (m0 + nn) * DIM + c4;
    float4 qv = *(const float4*)&q[base];
    float4 nv = {0.f, 0.f, 0.f, 0.f}, dv = {0.f, 0.f, 0.f, 0.f};
#pragma unroll
    for (int s = 0; s < 8; ++s) {
      float4 a = *(const float4*)&nump[s * NTOK * DIM + base];
      float4 d = *(const float4*)&denp[s * NTOK * DIM + base];
      nv.x += a.x; nv.y += a.y; nv.z += a.z; nv.w += a.w;
      dv.x += d.x; dv.y += d.y; dv.z += d.z; dv.w += d.w;
    }
    At[c4 + 0][nn] = qv.x * (nv.x / dv.x);
    At[c4 + 1][nn] = qv.y * (nv.y / dv.y);
    At[c4 + 2][nn] = qv.z * (nv.z / dv.z);
    At[c4 + 3][nn] = qv.w * (nv.w / dv.w);
  }
  {
    int r = tid >> 1, kq = (tid & 1) * 64;
#pragma unroll
    for (int j = 0; j < 16; ++j) {
      float4 v = *(const float4*)&wo[r * DIM + kq + j * 4];
      Bs[kq + j * 4 + 0][r] = v.x; Bs[kq + j * 4 + 1][r] = v.y;
      Bs[kq + j * 4 + 2][r] = v.z; Bs[kq + j * 4 + 3][r] = v.w;
    }
  }
  __syncthreads();

  int ty = tid >> 5, tx = tid & 31;
  float acc[4] = {0.f, 0.f, 0.f, 0.f};
#pragma unroll 4
  for (int kk = 0; kk < DIM; ++kk) {
    float a = At[kk][ty];
    float4 b4 = *(const float4*)&Bs[kk][tx * 4];
    acc[0] = fmaf(a, b4.x, acc[0]);
    acc[1] = fmaf(a, b4.y, acc[1]);
    acc[2] = fmaf(a, b4.z, acc[2]);
    acc[3] = fmaf(a, b4.w, acc[3]);
  }
  int gn = m0 + ty;
  int c0 = tx * 4;
  float4 bias = *(const float4*)&bo[c0];
  float o0 = acc[0] + bias.x + x[(c0 + 0) * NTOK + gn];
  float o1 = acc[1] + bias.y + x[(c0 + 1) * NTOK + gn];
  float o2 = acc[2] + bias.z + x[(c0 + 2) * NTOK + gn];
  float o3 = acc[3] + bias.w + x[(c0 + 3) * NTOK + gn];

  // out-init: out^T = t2 + b2f (ff2 partials atomically added by K4)
  float4 bf = *(const float4*)&b2f[c0];
  out[(c0 + 0) * NTOK + gn] = o0 + bf.x;
  out[(c0 + 1) * NTOK + gn] = o1 + bf.y;
  out[(c0 + 2) * NTOK + gn] = o2 + bf.z;
  out[(c0 + 3) * NTOK + gn] = o3 + bf.w;

  // LN2 (32 lanes per row)
  float s = o0 + o1 + o2 + o3;
  float ss = o0 * o0 + o1 * o1 + o2 * o2 + o3 * o3;
#pragma unroll
  for (int off = 1; off < 32; off <<= 1) {
    s += __shfl_xor(s, off);
    ss += __shfl_xor(ss, off);
  }
  float mu = s * (1.0f / DIM);
  float var = ss * (1.0f / DIM) - mu * mu;
  float rs = rsqrtf(var + 1e-5f);
  float4 gg = *(const float4*)&g2[c0];
  float4 bb = *(const float4*)&b2n[c0];
  float4 f;
  f.x = (o0 - mu) * rs * gg.x + bb.x;
  f.y = (o1 - mu) * rs * gg.y + bb.y;
  f.z = (o2 - mu) * rs * gg.z + bb.z;
  f.w = (o3 - mu) * rs * gg.w + bb.w;
  *(float4*)&fn[gn * DIM + c0] = f;
}

// ========== K4: ff1(gelu)+ff2 fused, grid (25, 8), 256 thr, atomic accumulate ==========
__global__ __launch_bounds__(256) void ff_fused(
    const float* __restrict__ fn, const float* __restrict__ w1,
    const float* __restrict__ b1f, const float* __restrict__ w2,
    float* __restrict__ out) {
  __shared__ float Fs[DIM][32];    // fn tile, k-major
  __shared__ float W1s[DIM][64];   // w1 slice k-major; reused as W2s[64][128]
  __shared__ float P[32][65];      // ff1 tile (gelu'd), row-major padded
  int tid = threadIdx.x;
  int m0 = blockIdx.x * 32, f0 = blockIdx.y * 64;

  {
    int r = tid >> 3, kq = (tid & 7) * 16;
    int gm = min(m0 + r, NTOK - 1);
#pragma unroll
    for (int j = 0; j < 4; ++j) {
      float4 v = *(const float4*)&fn[gm * DIM + kq + j * 4];
      Fs[kq + j * 4 + 0][r] = v.x; Fs[kq + j * 4 + 1][r] = v.y;
      Fs[kq + j * 4 + 2][r] = v.z; Fs[kq + j * 4 + 3][r] = v.w;
    }
    int rw = tid >> 2, kw = (tid & 3) * 32;
#pragma unroll
    for (int j = 0; j < 8; ++j) {
      float4 v = *(const float4*)&w1[(f0 + rw) * DIM + kw + j * 4];
      W1s[kw + j * 4 + 0][rw] = v.x; W1s[kw + j * 4 + 1][rw] = v.y;
      W1s[kw + j * 4 + 2][rw] = v.z; W1s[kw + j * 4 + 3][rw] = v.w;
    }
  }
  __syncthreads();

  int ty = tid >> 4, tx = tid & 15;   // 2 rows x 4 f per thread
  float acc1[2][4] = {};
#pragma unroll 4
  for (int kk = 0; kk < DIM; ++kk) {
    float2 a2 = *(const float2*)&Fs[kk][ty * 2];
    float4 b4 = *(const float4*)&W1s[kk][tx * 4];
    float av[2] = {a2.x, a2.y};
    float bv[4] = {b4.x, b4.y, b4.z, b4.w};
#pragma unroll
    for (int i = 0; i < 2; ++i)
#pragma unroll
      for (int j = 0; j < 4; ++j) acc1[i][j] = fmaf(av[i], bv[j], acc1[i][j]);
  }
  float4 b1v = *(const float4*)&b1f[f0 + tx * 4];
  float bb[4] = {b1v.x, b1v.y, b1v.z, b1v.w};
  float ge[2][4];
#pragma unroll
  for (int i = 0; i < 2; ++i)
#pragma unroll
    for (int j = 0; j < 4; ++j) {
      float v = acc1[i][j] + bb[j];
      ge[i][j] = 0.5f * v * (1.0f + erff(v * 0.70710678118654752f));
    }
  __syncthreads();   // done reading W1s/Fs

  // write P; stage w2 slice (transposed) into W1s space
#pragma unroll
  for (int i = 0; i < 2; ++i)
#pragma unroll
    for (int j = 0; j < 4; ++j) P[ty * 2 + i][tx * 4 + j] = ge[i][j];
  float* W2s = &W1s[0][0];  // [64][128]
  {
    int c = tid >> 1, fq = (tid & 1) * 32;
#pragma unroll
    for (int j = 0; j < 8; ++j) {
      float4 v = *(const float4*)&w2[c * FFD + f0 + fq + j * 4];
      W2s[(fq + j * 4 + 0) * DIM + c] = v.x;
      W2s[(fq + j * 4 + 1) * DIM + c] = v.y;
      W2s[(fq + j * 4 + 2) * DIM + c] = v.z;
      W2s[(fq + j * 4 + 3) * DIM + c] = v.w;
    }
  }
  __syncthreads();

  // ff2 partial: each thread 1 row x 16 c over this block's 64 f
  int row = tid & 31, cb = (tid >> 5) * 16;
  float acc2[16] = {};
  for (int f = 0; f < 64; ++f) {
    float pvv = P[row][f];
    const float* wr = &W2s[f * DIM + cb];
#pragma unroll
    for (int j4 = 0; j4 < 4; ++j4) {
      float4 wv = *(const float4*)&wr[j4 * 4];
      acc2[j4 * 4 + 0] = fmaf(pvv, wv.x, acc2[j4 * 4 + 0]);
      acc2[j4 * 4 + 1] = fmaf(pvv, wv.y, acc2[j4 * 4 + 1]);
      acc2[j4 * 4 + 2] = fmaf(pvv, wv.z, acc2[j4 * 4 + 2]);
      acc2[j4 * 4 + 3] = fmaf(pvv, wv.w, acc2[j4 * 4 + 3]);
    }
  }
  if (m0 + row < NTOK) {
#pragma unroll
    for (int j = 0; j < 16; ++j)
      atomicAdd(&out[(cb + j) * NTOK + m0 + row], acc2[j]);
  }
}

extern "C" void kernel_launch(void* const* d_in, const int* in_sizes, int n_in,
                              void* d_out, int out_size, void* d_ws, size_t ws_size,
                              hipStream_t stream) {
  const float* x   = (const float*)d_in[0];
  const float* wq  = (const float*)d_in[1];
  const float* wk  = (const float*)d_in[2];
  const float* wv  = (const float*)d_in[3];
  const float* wo  = (const float*)d_in[4];
  const float* bo  = (const float*)d_in[5];
  const float* pu  = (const float*)d_in[6];
  const float* pv  = (const float*)d_in[7];
  const float* g1  = (const float*)d_in[8];
  const float* b1n = (const float*)d_in[9];
  const float* g2  = (const float*)d_in[10];
  const float* b2n = (const float*)d_in[11];
  const float* w1  = (const float*)d_in[12];
  const float* b1f = (const float*)d_in[13];
  const float* w2  = (const float*)d_in[14];
  const float* b2f = (const float*)d_in[15];
  float* out = (float*)d_out;

  float* ws = (float*)d_ws;
  float* q    = ws;                 // [784,128]
  float* ek   = ws + 100352;        // [784,128]
  float* vv   = ws + 200704;        // [784,128]
  float* fn   = ws + 301056;        // [784,128]
  float* W    = ws + 401408;        // [784,784]
  float* nump = ws + 1016064;       // [8,784,128]
  float* denp = ws + 1818880;       // [8,784,128]

  posw_qkv2<<<247, 256, 0, stream>>>(pu, pv, W, x, g1, b1n, wq, wk, wv, q, ek, vv);
  agg8<<<dim3(13, 2, 8), 256, 0, stream>>>(W, ek, vv, nump, denp);
  gate_proj_ln<<<98, 256, 0, stream>>>(q, nump, denp, wo, bo, x, g2, b2n, b2f, fn, out);
  ff_fused<<<dim3(25, 8), 256, 0, stream>>>(fn, w1, b1f, w2, out);
}

// Round 8
// 50.351 us; speedup vs baseline: 5.6890x; 1.0477x over previous
//
#include <hip/hip_runtime.h>
#include <math.h>

#define NTOK 784
#define DIM 128
#define FFD 512

// ========== K1: posw (325 blocks, 32x64) || LN1+qkv (150 blocks, 32 rows) ==========
__global__ __launch_bounds__(256) void posw_qkv3(
    const float* __restrict__ pu, const float* __restrict__ pv, float* __restrict__ W,
    const float* __restrict__ x, const float* __restrict__ g, const float* __restrict__ b,
    const float* __restrict__ wq, const float* __restrict__ wk, const float* __restrict__ wv,
    float* __restrict__ q, float* __restrict__ ek, float* __restrict__ vv) {
  __shared__ float smem[12288];  // 48 KB union
  int tid = threadIdx.x;

  if (blockIdx.x < 325) {
    // posw: 32x64 tile, full K staged once
    float (*As)[32] = (float(*)[32])smem;           // [128][32]
    float (*Bs)[64] = (float(*)[64])(smem + 4096);  // [128][64]
    int m0 = (blockIdx.x % 25) * 32, n0 = (blockIdx.x / 25) * 64;
    {
      int r = tid >> 3, kq = (tid & 7) * 16;
      int gm = min(m0 + r, NTOK - 1);
#pragma unroll
      for (int j = 0; j < 4; ++j) {
        float4 a = *(const float4*)&pu[gm * DIM + kq + j * 4];
        As[kq + j * 4 + 0][r] = a.x; As[kq + j * 4 + 1][r] = a.y;
        As[kq + j * 4 + 2][r] = a.z; As[kq + j * 4 + 3][r] = a.w;
      }
      int rb = tid >> 2, kb = (tid & 3) * 32;
      int gn = min(n0 + rb, NTOK - 1);
#pragma unroll
      for (int j = 0; j < 8; ++j) {
        float4 v = *(const float4*)&pv[gn * DIM + kb + j * 4];
        Bs[kb + j * 4 + 0][rb] = v.x; Bs[kb + j * 4 + 1][rb] = v.y;
        Bs[kb + j * 4 + 2][rb] = v.z; Bs[kb + j * 4 + 3][rb] = v.w;
      }
    }
    __syncthreads();
    int tx = tid & 15, ty = tid >> 4;  // 2 rows x 4 cols per thread
    float acc[2][4] = {};
#pragma unroll 8
    for (int kk = 0; kk < DIM; ++kk) {
      float2 a2 = *(const float2*)&As[kk][ty * 2];
      float4 b4 = *(const float4*)&Bs[kk][tx * 4];
      float av[2] = {a2.x, a2.y};
      float bv[4] = {b4.x, b4.y, b4.z, b4.w};
#pragma unroll
      for (int i = 0; i < 2; ++i)
#pragma unroll
        for (int j = 0; j < 4; ++j) acc[i][j] = fmaf(av[i], bv[j], acc[i][j]);
    }
    int c0 = n0 + tx * 4;
    if (c0 + 3 < NTOK) {
#pragma unroll
      for (int i = 0; i < 2; ++i) {
        int gr = m0 + ty * 2 + i;
        if (gr < NTOK) {
          float4 o = {expf(acc[i][0]), expf(acc[i][1]), expf(acc[i][2]), expf(acc[i][3])};
          *(float4*)&W[gr * NTOK + c0] = o;
        }
      }
    }
  } else {
    // qkv: LN1 + one of {q,k,v} half, 32-row tile
    float (*Xs)[32] = (float(*)[32])smem;            // [128][32]
    float (*Bq)[64] = (float(*)[64])(smem + 4096);   // [64][64]
    float* redS = smem + 8192;                       // [8][32]
    float* redQ = smem + 8448;
    int bid = blockIdx.x - 325;
    int m0 = (bid % 25) * 32;
    int ct = bid / 25;
    int wsel = ct >> 1;
    int n0 = (ct & 1) * 64;
    const float* B = (wsel == 0) ? wq : (wsel == 1) ? wk : wv;

    if (m0 + 32 <= NTOK) {
#pragma unroll
      for (int it = 0; it < 4; ++it) {
        int idx = it * 256 + tid;
        int c = idx >> 3, j4 = (idx & 7) * 4;
        float4 v = *(const float4*)&x[c * NTOK + m0 + j4];
        Xs[c][j4 + 0] = v.x; Xs[c][j4 + 1] = v.y; Xs[c][j4 + 2] = v.z; Xs[c][j4 + 3] = v.w;
      }
    } else {
#pragma unroll
      for (int it = 0; it < 4; ++it) {
        int idx = it * 256 + tid;
        int c = idx >> 3, j4 = (idx & 7) * 4;
#pragma unroll
        for (int u = 0; u < 4; ++u) {
          int n = min(m0 + j4 + u, NTOK - 1);
          Xs[c][j4 + u] = x[c * NTOK + n];
        }
      }
    }
    __syncthreads();

    int n = tid & 31, grp = tid >> 5;   // 8 groups x 16 channels
    float s = 0.f, ss = 0.f;
    for (int c = grp * 16; c < grp * 16 + 16; ++c) { float v = Xs[c][n]; s += v; ss += v * v; }
    redS[grp * 32 + n] = s; redQ[grp * 32 + n] = ss;
    __syncthreads();
    float sum = 0.f, sq = 0.f;
#pragma unroll
    for (int gi = 0; gi < 8; ++gi) { sum += redS[gi * 32 + n]; sq += redQ[gi * 32 + n]; }
    float mu = sum * (1.0f / DIM);
    float var = sq * (1.0f / DIM) - mu * mu;
    float rs = rsqrtf(var + 1e-5f);
    for (int c = grp * 16; c < grp * 16 + 16; ++c)
      Xs[c][n] = (Xs[c][n] - mu) * rs * g[c] + b[c];

    int tx = tid & 15, ty = tid >> 4;
    float acc[2][4] = {};
#pragma unroll
    for (int h = 0; h < 2; ++h) {
      {
        int r = tid >> 2, kq = (tid & 3) * 16;
#pragma unroll
        for (int j = 0; j < 4; ++j) {
          float4 v = *(const float4*)&B[(n0 + r) * DIM + h * 64 + kq + j * 4];
          Bq[kq + j * 4 + 0][r] = v.x; Bq[kq + j * 4 + 1][r] = v.y;
          Bq[kq + j * 4 + 2][r] = v.z; Bq[kq + j * 4 + 3][r] = v.w;
        }
      }
      __syncthreads();
#pragma unroll 4
      for (int kk = 0; kk < 64; ++kk) {
        float2 a2 = *(const float2*)&Xs[h * 64 + kk][ty * 2];
        float4 b4 = *(const float4*)&Bq[kk][tx * 4];
        float av[2] = {a2.x, a2.y};
        float bv[4] = {b4.x, b4.y, b4.z, b4.w};
#pragma unroll
        for (int i = 0; i < 2; ++i)
#pragma unroll
          for (int j = 0; j < 4; ++j) acc[i][j] = fmaf(av[i], bv[j], acc[i][j]);
      }
      __syncthreads();
    }
    int c0 = n0 + tx * 4;
    float* dst = (wsel == 0) ? q : (wsel == 1) ? ek : vv;
#pragma unroll
    for (int i = 0; i < 2; ++i) {
      int gr = m0 + ty * 2 + i;
      if (gr < NTOK) {
        float4 o;
        if (wsel == 0) {
          o.x = 1.0f / (1.0f + expf(-acc[i][0]));
          o.y = 1.0f / (1.0f + expf(-acc[i][1]));
          o.z = 1.0f / (1.0f + expf(-acc[i][2]));
          o.w = 1.0f / (1.0f + expf(-acc[i][3]));
        } else if (wsel == 1) {
          o.x = expf(acc[i][0]); o.y = expf(acc[i][1]);
          o.z = expf(acc[i][2]); o.w = expf(acc[i][3]);
        } else {
          o.x = acc[i][0]; o.y = acc[i][1]; o.z = acc[i][2]; o.w = acc[i][3];
        }
        *(float4*)&dst[gr * DIM + c0] = o;
      }
    }
  }
}

// ========== K2: agg, split-8, 32-row tiles, grid (25,2,8), 256 thr ==========
__global__ __launch_bounds__(256) void agg32(
    const float* __restrict__ W, const float* __restrict__ ek,
    const float* __restrict__ vv, float* __restrict__ nump, float* __restrict__ denp) {
  __shared__ float As[96][32];
  __shared__ float Bn[96][64];
  __shared__ float Bd[96][64];
  int tid = threadIdx.x;
  int m0 = blockIdx.x * 32, d0 = blockIdx.y * 64, sp = blockIdx.z;
  int tx = tid & 15, ty = tid >> 4;         // 2 rows x 4 cols
  int ra = tid >> 3, ka = (tid & 7) * 4;    // A: 32 rows, 32 k-cols per chunk
  int kb = tid >> 3, db = (tid & 7) * 8;    // B: 32 k-rows, 64 d per chunk
  int gm = min(m0 + ra, NTOK - 1);
  float an[2][4] = {}, ad[2][4] = {};
  int tlo = (sp * 25) / 8, thi = ((sp + 1) * 25) / 8;
  for (int base = tlo; base < thi; base += 3) {
    int nt = min(3, thi - base);
    for (int t = 0; t < nt; ++t) {
      int k0 = (base + t) * 32;
      int lk = t * 32;
      if (k0 + 32 <= NTOK) {
        float4 a = *(const float4*)&W[gm * NTOK + k0 + ka];
        As[lk + ka + 0][ra] = a.x; As[lk + ka + 1][ra] = a.y;
        As[lk + ka + 2][ra] = a.z; As[lk + ka + 3][ra] = a.w;
        int gk = k0 + kb;
        float4 e0 = *(const float4*)&ek[gk * DIM + d0 + db];
        float4 e1 = *(const float4*)&ek[gk * DIM + d0 + db + 4];
        float4 w0 = *(const float4*)&vv[gk * DIM + d0 + db];
        float4 w1_ = *(const float4*)&vv[gk * DIM + d0 + db + 4];
        Bd[lk + kb][db + 0] = e0.x; Bd[lk + kb][db + 1] = e0.y;
        Bd[lk + kb][db + 2] = e0.z; Bd[lk + kb][db + 3] = e0.w;
        Bd[lk + kb][db + 4] = e1.x; Bd[lk + kb][db + 5] = e1.y;
        Bd[lk + kb][db + 6] = e1.z; Bd[lk + kb][db + 7] = e1.w;
        Bn[lk + kb][db + 0] = e0.x * w0.x; Bn[lk + kb][db + 1] = e0.y * w0.y;
        Bn[lk + kb][db + 2] = e0.z * w0.z; Bn[lk + kb][db + 3] = e0.w * w0.w;
        Bn[lk + kb][db + 4] = e1.x * w1_.x; Bn[lk + kb][db + 5] = e1.y * w1_.y;
        Bn[lk + kb][db + 6] = e1.z * w1_.z; Bn[lk + kb][db + 7] = e1.w * w1_.w;
      } else {
#pragma unroll
        for (int j = 0; j < 4; ++j) {
          int gk = k0 + ka + j;
          As[lk + ka + j][ra] = (gk < NTOK) ? W[gm * NTOK + gk] : 0.f;
        }
        int gk = k0 + kb;
        if (gk < NTOK) {
          float4 e0 = *(const float4*)&ek[gk * DIM + d0 + db];
          float4 e1 = *(const float4*)&ek[gk * DIM + d0 + db + 4];
          float4 w0 = *(const float4*)&vv[gk * DIM + d0 + db];
          float4 w1_ = *(const float4*)&vv[gk * DIM + d0 + db + 4];
          Bd[lk + kb][db + 0] = e0.x; Bd[lk + kb][db + 1] = e0.y;
          Bd[lk + kb][db + 2] = e0.z; Bd[lk + kb][db + 3] = e0.w;
          Bd[lk + kb][db + 4] = e1.x; Bd[lk + kb][db + 5] = e1.y;
          Bd[lk + kb][db + 6] = e1.z; Bd[lk + kb][db + 7] = e1.w;
          Bn[lk + kb][db + 0] = e0.x * w0.x; Bn[lk + kb][db + 1] = e0.y * w0.y;
          Bn[lk + kb][db + 2] = e0.z * w0.z; Bn[lk + kb][db + 3] = e0.w * w0.w;
          Bn[lk + kb][db + 4] = e1.x * w1_.x; Bn[lk + kb][db + 5] = e1.y * w1_.y;
          Bn[lk + kb][db + 6] = e1.z * w1_.z; Bn[lk + kb][db + 7] = e1.w * w1_.w;
        } else {
#pragma unroll
          for (int j = 0; j < 8; ++j) { Bd[lk + kb][db + j] = 0.f; Bn[lk + kb][db + j] = 0.f; }
        }
      }
    }
    __syncthreads();
    int nk = nt * 32;
    for (int kk = 0; kk < nk; ++kk) {
      float2 a2 = *(const float2*)&As[kk][ty * 2];
      float4 n4 = *(const float4*)&Bn[kk][tx * 4];
      float4 d4 = *(const float4*)&Bd[kk][tx * 4];
      float av[2] = {a2.x, a2.y};
      float nv[4] = {n4.x, n4.y, n4.z, n4.w};
      float dv[4] = {d4.x, d4.y, d4.z, d4.w};
#pragma unroll
      for (int i = 0; i < 2; ++i)
#pragma unroll
        for (int j = 0; j < 4; ++j) {
          an[i][j] = fmaf(av[i], nv[j], an[i][j]);
          ad[i][j] = fmaf(av[i], dv[j], ad[i][j]);
        }
    }
    __syncthreads();
  }
#pragma unroll
  for (int i = 0; i < 2; ++i) {
    int gr = m0 + ty * 2 + i;
    if (gr < NTOK) {
      float4 on = {an[i][0], an[i][1], an[i][2], an[i][3]};
      float4 od = {ad[i][0], ad[i][1], ad[i][2], ad[i][3]};
      *(float4*)&nump[(sp * NTOK + gr) * DIM + d0 + tx * 4] = on;
      *(float4*)&denp[(sp * NTOK + gr) * DIM + d0 + tx * 4] = od;
    }
  }
}

// ========== K3: gate + O-proj + residual + LN2 + out-init, 98 blocks x 256 thr ==========
__global__ __launch_bounds__(256) void gate_proj_ln(
    const float* __restrict__ q, const float* __restrict__ nump,
    const float* __restrict__ denp, const float* __restrict__ wo,
    const float* __restrict__ bo, const float* __restrict__ x,
    const float* __restrict__ g2, const float* __restrict__ b2n,
    const float* __restrict__ b2f, float* __restrict__ fn, float* __restrict__ out) {
  __shared__ float At[DIM][9];     // attn tile k-major, 8 rows
  __shared__ float Bs[DIM][DIM];   // full wo, k-major
  int tid = threadIdx.x;
  int m0 = blockIdx.x * 8;         // 98*8 = 784

  {
    int nn = tid >> 5, c4 = (tid & 31) * 4;
    int base = (m0 + nn) * DIM + c4;
    float4 qv = *(const float4*)&q[base];
    float4 nv = {0.f, 0.f, 0.f, 0.f}, dv = {0.f, 0.f, 0.f, 0.f};
#pragma unroll
    for (int s = 0; s < 8; ++s) {
      float4 a = *(const float4*)&nump[s * NTOK * DIM + base];
      float4 d = *(const float4*)&denp[s * NTOK * DIM + base];
      nv.x += a.x; nv.y += a.y; nv.z += a.z; nv.w += a.w;
      dv.x += d.x; dv.y += d.y; dv.z += d.z; dv.w += d.w;
    }
    At[c4 + 0][nn] = qv.x * (nv.x / dv.x);
    At[c4 + 1][nn] = qv.y * (nv.y / dv.y);
    At[c4 + 2][nn] = qv.z * (nv.z / dv.z);
    At[c4 + 3][nn] = qv.w * (nv.w / dv.w);
  }
  {
    int r = tid >> 1, kq = (tid & 1) * 64;
#pragma unroll
    for (int j = 0; j < 16; ++j) {
      float4 v = *(const float4*)&wo[r * DIM + kq + j * 4];
      Bs[kq + j * 4 + 0][r] = v.x; Bs[kq + j * 4 + 1][r] = v.y;
      Bs[kq + j * 4 + 2][r] = v.z; Bs[kq + j * 4 + 3][r] = v.w;
    }
  }
  __syncthreads();

  int ty = tid >> 5, tx = tid & 31;
  float acc[4] = {0.f, 0.f, 0.f, 0.f};
#pragma unroll 4
  for (int kk = 0; kk < DIM; ++kk) {
    float a = At[kk][ty];
    float4 b4 = *(const float4*)&Bs[kk][tx * 4];
    acc[0] = fmaf(a, b4.x, acc[0]);
    acc[1] = fmaf(a, b4.y, acc[1]);
    acc[2] = fmaf(a, b4.z, acc[2]);
    acc[3] = fmaf(a, b4.w, acc[3]);
  }
  int gn = m0 + ty;
  int c0 = tx * 4;
  float4 bias = *(const float4*)&bo[c0];
  float o0 = acc[0] + bias.x + x[(c0 + 0) * NTOK + gn];
  float o1 = acc[1] + bias.y + x[(c0 + 1) * NTOK + gn];
  float o2 = acc[2] + bias.z + x[(c0 + 2) * NTOK + gn];
  float o3 = acc[3] + bias.w + x[(c0 + 3) * NTOK + gn];

  // out-init: out^T = t2 + b2f (ff2 partials atomically added by K4)
  float4 bf = *(const float4*)&b2f[c0];
  out[(c0 + 0) * NTOK + gn] = o0 + bf.x;
  out[(c0 + 1) * NTOK + gn] = o1 + bf.y;
  out[(c0 + 2) * NTOK + gn] = o2 + bf.z;
  out[(c0 + 3) * NTOK + gn] = o3 + bf.w;

  // LN2 (32 lanes per row)
  float s = o0 + o1 + o2 + o3;
  float ss = o0 * o0 + o1 * o1 + o2 * o2 + o3 * o3;
#pragma unroll
  for (int off = 1; off < 32; off <<= 1) {
    s += __shfl_xor(s, off);
    ss += __shfl_xor(ss, off);
  }
  float mu = s * (1.0f / DIM);
  float var = ss * (1.0f / DIM) - mu * mu;
  float rs = rsqrtf(var + 1e-5f);
  float4 gg = *(const float4*)&g2[c0];
  float4 bb = *(const float4*)&b2n[c0];
  float4 f;
  f.x = (o0 - mu) * rs * gg.x + bb.x;
  f.y = (o1 - mu) * rs * gg.y + bb.y;
  f.z = (o2 - mu) * rs * gg.z + bb.z;
  f.w = (o3 - mu) * rs * gg.w + bb.w;
  *(float4*)&fn[gn * DIM + c0] = f;
}

// ========== K4: ff1(gelu)+ff2 fused, grid (49, 8), 256 thr, atomic accumulate ==========
__global__ __launch_bounds__(256) void ff_fused16(
    const float* __restrict__ fn, const float* __restrict__ w1,
    const float* __restrict__ b1f, const float* __restrict__ w2,
    float* __restrict__ out) {
  __shared__ float Fs[DIM][16];    // fn tile, k-major (8 KB)
  __shared__ float W1s[DIM][64];   // w1 slice k-major (32 KB); reused as W2s[64][128]
  __shared__ float P[16][65];      // ff1 tile (gelu'd), padded (4.2 KB)
  int tid = threadIdx.x;
  int m0 = blockIdx.x * 16, f0 = blockIdx.y * 64;   // 49*16 = 784 exact

  {
    int r = tid >> 4, kq = (tid & 15) * 8;
#pragma unroll
    for (int j = 0; j < 2; ++j) {
      float4 v = *(const float4*)&fn[(m0 + r) * DIM + kq + j * 4];
      Fs[kq + j * 4 + 0][r] = v.x; Fs[kq + j * 4 + 1][r] = v.y;
      Fs[kq + j * 4 + 2][r] = v.z; Fs[kq + j * 4 + 3][r] = v.w;
    }
    int rw = tid >> 2, kw = (tid & 3) * 32;
#pragma unroll
    for (int j = 0; j < 8; ++j) {
      float4 v = *(const float4*)&w1[(f0 + rw) * DIM + kw + j * 4];
      W1s[kw + j * 4 + 0][rw] = v.x; W1s[kw + j * 4 + 1][rw] = v.y;
      W1s[kw + j * 4 + 2][rw] = v.z; W1s[kw + j * 4 + 3][rw] = v.w;
    }
  }
  __syncthreads();

  // ff1: 1 row x 4 f per thread
  int row = tid >> 4, f4 = (tid & 15) * 4;
  float acc1[4] = {};
#pragma unroll 4
  for (int kk = 0; kk < DIM; ++kk) {
    float a = Fs[kk][row];
    float4 b4 = *(const float4*)&W1s[kk][f4];
    acc1[0] = fmaf(a, b4.x, acc1[0]);
    acc1[1] = fmaf(a, b4.y, acc1[1]);
    acc1[2] = fmaf(a, b4.z, acc1[2]);
    acc1[3] = fmaf(a, b4.w, acc1[3]);
  }
  float4 b1v = *(const float4*)&b1f[f0 + f4];
  float bb[4] = {b1v.x, b1v.y, b1v.z, b1v.w};
  float ge[4];
#pragma unroll
  for (int j = 0; j < 4; ++j) {
    float v = acc1[j] + bb[j];
    ge[j] = 0.5f * v * (1.0f + erff(v * 0.70710678118654752f));
  }
  __syncthreads();   // done reading W1s/Fs

#pragma unroll
  for (int j = 0; j < 4; ++j) P[row][f4 + j] = ge[j];
  float* W2s = &W1s[0][0];  // [64][128]
  {
    int c = tid >> 1, fq = (tid & 1) * 32;
#pragma unroll
    for (int j = 0; j < 8; ++j) {
      float4 v = *(const float4*)&w2[c * FFD + f0 + fq + j * 4];
      W2s[(fq + j * 4 + 0) * DIM + c] = v.x;
      W2s[(fq + j * 4 + 1) * DIM + c] = v.y;
      W2s[(fq + j * 4 + 2) * DIM + c] = v.z;
      W2s[(fq + j * 4 + 3) * DIM + c] = v.w;
    }
  }
  __syncthreads();

  // ff2 partial: 1 row x 8 c per thread
  int r2 = tid & 15, cb = (tid >> 4) * 8;
  float acc2[8] = {};
  for (int f = 0; f < 64; ++f) {
    float pvv = P[r2][f];
    const float* wr = &W2s[f * DIM + cb];
#pragma unroll
    for (int j4 = 0; j4 < 2; ++j4) {
      float4 wv = *(const float4*)&wr[j4 * 4];
      acc2[j4 * 4 + 0] = fmaf(pvv, wv.x, acc2[j4 * 4 + 0]);
      acc2[j4 * 4 + 1] = fmaf(pvv, wv.y, acc2[j4 * 4 + 1]);
      acc2[j4 * 4 + 2] = fmaf(pvv, wv.z, acc2[j4 * 4 + 2]);
      acc2[j4 * 4 + 3] = fmaf(pvv, wv.w, acc2[j4 * 4 + 3]);
    }
  }
#pragma unroll
  for (int j = 0; j < 8; ++j)
    atomicAdd(&out[(cb + j) * NTOK + m0 + r2], acc2[j]);
}

extern "C" void kernel_launch(void* const* d_in, const int* in_sizes, int n_in,
                              void* d_out, int out_size, void* d_ws, size_t ws_size,
                              hipStream_t stream) {
  const float* x   = (const float*)d_in[0];
  const float* wq  = (const float*)d_in[1];
  const float* wk  = (const float*)d_in[2];
  const float* wv  = (const float*)d_in[3];
  const float* wo  = (const float*)d_in[4];
  const float* bo  = (const float*)d_in[5];
  const float* pu  = (const float*)d_in[6];
  const float* pv  = (const float*)d_in[7];
  const float* g1  = (const float*)d_in[8];
  const float* b1n = (const float*)d_in[9];
  const float* g2  = (const float*)d_in[10];
  const float* b2n = (const float*)d_in[11];
  const float* w1  = (const float*)d_in[12];
  const float* b1f = (const float*)d_in[13];
  const float* w2  = (const float*)d_in[14];
  const float* b2f = (const float*)d_in[15];
  float* out = (float*)d_out;

  float* ws = (float*)d_ws;
  float* q    = ws;                 // [784,128]
  float* ek   = ws + 100352;        // [784,128]
  float* vv   = ws + 200704;        // [784,128]
  float* fn   = ws + 301056;        // [784,128]
  float* W    = ws + 401408;        // [784,784]
  float* nump = ws + 1016064;       // [8,784,128]
  float* denp = ws + 1818880;       // [8,784,128]

  posw_qkv3<<<475, 256, 0, stream>>>(pu, pv, W, x, g1, b1n, wq, wk, wv, q, ek, vv);
  agg32<<<dim3(25, 2, 8), 256, 0, stream>>>(W, ek, vv, nump, denp);
  gate_proj_ln<<<98, 256, 0, stream>>>(q, nump, denp, wo, bo, x, g2, b2n, b2f, fn, out);
  ff_fused16<<<dim3(49, 8), 256, 0, stream>>>(fn, w1, b1f, w2, out);
}